// Round 6
// baseline (301.357 us; speedup 1.0000x reference)
//
#include <hip/hip_runtime.h>
#include <stdint.h>

// Conv2d 3x3 valid, C_in=8, C_out=8, H=W=2048, fp32.
// x: (8, 2048, 2048), weight: (8, 8, 3, 3), out: (8, 2046, 2046).
//
// v4: LDS double-buffered ci-pipeline with hardware async staging.
//   - block = 512 threads = one full-width output row-pair (2046 x 2 x 8co)
//   - per ci: 4 input rows x 2048 f32 staged to LDS via 32x
//     global_load_lds dwordx4 (4 per wave, zero VGPR for in-flight data)
//   - counted s_waitcnt vmcnt(4) + raw s_barrier: next stage's loads stay
//     in flight across the barrier (T3/T4); compute (576 FMA = 1152 cy)
//     hides the ~900 cy HBM/L3 latency within a single wave
//   - LDS 64KB -> 2 blocks/CU (16 waves/CU); ds_read_b128 conflict-free

#define H_IN   2048
#define W_IN   2048
#define H_OUT  2046
#define W_OUT  2046
#define CIN    8
#define COUT   8
#define PLANE  ((size_t)H_IN * W_IN)

template<int N>
__device__ __forceinline__ void vm_wait() {
    asm volatile("s_waitcnt vmcnt(%0)" :: "n"(N) : "memory");
}

__device__ __forceinline__
void compute_phase(float (&acc)[2][COUT][4],
                   const float* __restrict__ w, int ci,
                   const float (&buf)[4][W_IN], int ow, bool full) {
    float in[4][6];
    #pragma unroll
    for (int r = 0; r < 4; ++r) {
        const float4 v4 = *reinterpret_cast<const float4*>(&buf[r][ow]);  // ds_read_b128
        in[r][0] = v4.x; in[r][1] = v4.y; in[r][2] = v4.z; in[r][3] = v4.w;
        if (full) {
            const float2 v2 = *reinterpret_cast<const float2*>(&buf[r][ow + 4]); // ds_read_b64
            in[r][4] = v2.x; in[r][5] = v2.y;
        } else {
            in[r][4] = 0.0f; in[r][5] = 0.0f;   // tail tile: px 2,3 never stored
        }
    }
    // input row r feeds output row 0 with kh=r (r<3), row 1 with kh=r-1 (r>=1)
    #pragma unroll
    for (int r = 0; r < 4; ++r) {
        #pragma unroll
        for (int co = 0; co < COUT; ++co) {
            #pragma unroll
            for (int kw = 0; kw < 3; ++kw) {
                if (r < 3) {
                    const float wt = w[((co * CIN + ci) * 3 + r) * 3 + kw];
                    #pragma unroll
                    for (int px = 0; px < 4; ++px)
                        acc[0][co][px] = fmaf(wt, in[r][kw + px], acc[0][co][px]);
                }
                if (r >= 1) {
                    const float wt = w[((co * CIN + ci) * 3 + (r - 1)) * 3 + kw];
                    #pragma unroll
                    for (int px = 0; px < 4; ++px)
                        acc[1][co][px] = fmaf(wt, in[r][kw + px], acc[1][co][px]);
                }
            }
        }
    }
}

__global__ __launch_bounds__(512, 4)
void conv3x3_v4(const float* __restrict__ x,
                const float* __restrict__ w,
                float* __restrict__ out) {
    __shared__ float lds[2][4][W_IN];           // 64 KB, double-buffered ci plane

    const int tid  = threadIdx.x;
    const int wave = tid >> 6;
    const int lane = tid & 63;
    const int oh   = blockIdx.x * 2;            // 1023 blocks -> oh = 0..2044
    const int ow   = tid * 4;                   // 0..2044
    const bool full = (tid != 511);             // tail tile: 2 valid cols

    // stage ci's 4 input rows into lds[b]: 32 dwordx4 chunk-loads, 4 per wave.
    // j = wave*4+i: row = j>>3 (0..3), chunk = j&7 (256 floats each).
    // LDS dest is wave-uniform; HW adds lane*16B. Global src is per-lane.
#define STAGE(b, ci) do {                                                     \
        const float* _src = x + (size_t)(ci) * PLANE + (size_t)oh * W_IN;     \
        _Pragma("unroll")                                                     \
        for (int _i = 0; _i < 4; ++_i) {                                      \
            const int _j = wave * 4 + _i;                                     \
            const int _row = _j >> 3, _chunk = _j & 7;                        \
            const float* _g = _src + _row * W_IN + _chunk * 256 + lane * 4;   \
            __builtin_amdgcn_global_load_lds(                                 \
                (const __attribute__((address_space(1))) uint32_t*)_g,        \
                (__attribute__((address_space(3))) uint32_t*)&lds[b][_row][_chunk * 256], \
                16, 0, 0);                                                    \
        }                                                                     \
    } while (0)

    float acc[2][COUT][4];
    #pragma unroll
    for (int r = 0; r < 2; ++r)
        #pragma unroll
        for (int co = 0; co < COUT; ++co)
            #pragma unroll
            for (int p = 0; p < 4; ++p)
                acc[r][co][p] = 0.0f;

    STAGE(0, 0);                                 // prologue: ci=0 -> buf0

    #pragma unroll 1
    for (int k = 0; k < 4; ++k) {
        const int ci0 = 2 * k, ci1 = 2 * k + 1;

        // ---- phase ci0 (even): compute buf0, stage ci1 -> buf1 ----
        STAGE(1, ci1);
        vm_wait<4>();                            // ci0's 4 loads done; ci1's in flight
        __builtin_amdgcn_s_barrier();
        __builtin_amdgcn_sched_barrier(0);
        compute_phase(acc, w, ci0, lds[0], ow, full);
        __builtin_amdgcn_sched_barrier(0);
        __builtin_amdgcn_s_barrier();            // all waves done reading buf0

        // ---- phase ci1 (odd): compute buf1, stage ci0+2 -> buf0 ----
        if (k < 3) {
            STAGE(0, ci1 + 1);
            vm_wait<4>();
        } else {
            vm_wait<0>();                        // final phase: drain
        }
        __builtin_amdgcn_s_barrier();
        __builtin_amdgcn_sched_barrier(0);
        compute_phase(acc, w, ci1, lds[1], ow, full);
        __builtin_amdgcn_sched_barrier(0);
        __builtin_amdgcn_s_barrier();
    }
#undef STAGE

    // Epilogue. Even rows are 16B-aligned at ow (oh*2046 + ow ≡ 0 mod 4 for
    // even oh, ow ≡ 0 mod 4); odd rows are 8B-aligned -> float2 pairs.
    #pragma unroll
    for (int co = 0; co < COUT; ++co) {
        float* o0 = out + ((size_t)co * H_OUT + (size_t)oh) * W_OUT + ow;
        float* o1 = o0 + W_OUT;
        if (full) {
            *reinterpret_cast<float4*>(o0) =
                make_float4(acc[0][co][0], acc[0][co][1], acc[0][co][2], acc[0][co][3]);
            *reinterpret_cast<float2*>(o1)     = make_float2(acc[1][co][0], acc[1][co][1]);
            *reinterpret_cast<float2*>(o1 + 2) = make_float2(acc[1][co][2], acc[1][co][3]);
        } else {
            *reinterpret_cast<float2*>(o0) = make_float2(acc[0][co][0], acc[0][co][1]);
            *reinterpret_cast<float2*>(o1) = make_float2(acc[1][co][0], acc[1][co][1]);
        }
    }
}

extern "C" void kernel_launch(void* const* d_in, const int* in_sizes, int n_in,
                              void* d_out, int out_size, void* d_ws, size_t ws_size,
                              hipStream_t stream) {
    const float* x = (const float*)d_in[0];
    const float* w = (const float*)d_in[1];
    float* out = (float*)d_out;

    const int grid = H_OUT / 2;                 // 1023 blocks, one row-pair each
    conv3x3_v4<<<grid, 512, 0, stream>>>(x, w, out);
}